// Round 11
// baseline (100.300 us; speedup 1.0000x reference)
//
#include <hip/hip_runtime.h>

#define C2  2.8853900817779268f   // 2*log2(e)
#define L2E 1.4426950408889634f   // log2(e)

typedef float float2v __attribute__((ext_vector_type(2)));

__device__ __forceinline__ float2v pk_fma(float2v a, float2v b, float2v c) {
  float2v d;
  asm("v_pk_fma_f32 %0, %1, %2, %3" : "=v"(d) : "v"(a), "v"(b), "v"(c));
  return d;
}
// d.lo = a.lo*b.lo + c.lo ; d.hi = a.hi*b.lo + c.hi   (broadcast b.lo)
__device__ __forceinline__ float2v pk_fma_bl(float2v a, float2v b, float2v c) {
  float2v d;
  asm("v_pk_fma_f32 %0, %1, %2, %3 op_sel:[0,0,0] op_sel_hi:[1,0,1]"
      : "=v"(d) : "v"(a), "v"(b), "v"(c));
  return d;
}
// d.lo = a.lo*b.hi + c.lo ; d.hi = a.hi*b.hi + c.hi   (broadcast b.hi)
__device__ __forceinline__ float2v pk_fma_bh(float2v a, float2v b, float2v c) {
  float2v d;
  asm("v_pk_fma_f32 %0, %1, %2, %3 op_sel:[0,1,0] op_sel_hi:[1,1,1]"
      : "=v"(d) : "v"(a), "v"(b), "v"(c));
  return d;
}

// ---------------- Projection (outputs PRE-SCALED by C2):
// block = 16 rows x 16 d; grid = 384 row-groups x 4 d-groups = 1536 blocks, 16KB LDS.
__global__ __launch_bounds__(256) void proj_kernel(
    const float* __restrict__ inputs, const float* __restrict__ memory,
    const float* __restrict__ W_in, const float* __restrict__ b_in,
    const float* __restrict__ W_mem,
    float* __restrict__ in_item, float* __restrict__ mem_itemT)
{
  const int NIN = 2048;
  int blk = blockIdx.x;
  int dg = blk & 3;
  int r0 = (blk >> 2) * 16;
  int tid = threadIdx.x;
  int dl = tid & 15;            // d within group
  int rw = tid >> 4;            // row within block (0..15)
  int d  = dg * 16 + dl;

  __shared__ float4 wlds[16][64];   // W rows [dg*16 .. dg*16+16), swizzled

  bool is_in = (r0 < NIN);
  const float* Wsel  = is_in ? W_in  : W_mem;
  const float* Abase = is_in ? inputs : memory;
  int ar0 = is_in ? r0 : r0 - NIN;

  const float4* Wv = reinterpret_cast<const float4*>(Wsel + (size_t)dg * 16 * 256);
  #pragma unroll
  for (int u = 0; u < 4; ++u) {
    int e = tid + u * 256;       // 0..1023
    int j = e >> 6, k4 = e & 63;
    wlds[j][k4 ^ (j & 7)] = Wv[e];
  }
  float bias = is_in ? b_in[d] : 0.f;
  __syncthreads();

  const float4* A0 = reinterpret_cast<const float4*>(Abase + (size_t)(ar0 + rw) * 256);
  float2v acc = {0.f, 0.f};
  #pragma unroll 8
  for (int k4 = 0; k4 < 64; ++k4) {
    float4 w = wlds[dl][k4 ^ (dl & 7)];
    float4 a = A0[k4];
    acc = pk_fma(float2v{a.x, a.y}, float2v{w.x, w.y}, acc);
    acc = pk_fma(float2v{a.z, a.w}, float2v{w.z, w.w}, acc);
  }
  float val = (acc.x + acc.y + bias) * C2;
  int row = ar0 + rw;
  if (is_in) {
    in_item[(size_t)row * 64 + d] = val;
  } else {
    int b_ = row >> 10, m = row & 1023;
    mem_itemT[((size_t)(b_ * 16 + (d >> 2)) * 1024 + m) * 4 + (d & 3)] = val;
  }
}

// ---------------- Fused score+softmax+PV, BARRIER-FREE.
// One wave = one i-row (of a 4-row block) x one Tm slice. Lane = m within tile
// for score; lane = d-quad (4*lane) for PV. p handoff via wave-private LDS
// (ds_write -> uniform-addr broadcast ds_read, same-wave lgkm ordering).
__global__ __launch_bounds__(256, 6) void attn_kernel(
    const float* __restrict__ in_item,   // (B,Ti,64), pre-scaled
    const float* __restrict__ mem_itemT, // (B,16,Tm,4), pre-scaled, d-major
    const float* __restrict__ memory,    // (B,Tm,256)
    const int* __restrict__ in_len, const int* __restrict__ mem_len,
    const float* __restrict__ W_final,   // (64)
    float* __restrict__ o_part,          // (nsplit, B*Ti, 256)
    float* __restrict__ psum_part,       // (nsplit, B*Ti)
    int m_count, int shift)              // shift = log2(4*nsplit)
{
  const int Ti = 512, Tm = 1024, DM = 256;
  const int MT = 64;
  const int NT = m_count >> 6;
  int lin = blockIdx.x;
  int c = lin & ((1 << shift) - 1);   // XCD-clustered: lin&7 -> fixed b per XCD
  int b = c & 3;
  int z = c >> 2;
  int i0 = (lin >> shift) << 2;
  int m_begin = z * m_count;
  int tid = threadIdx.x;
  int lane = tid & 63;
  int wv = tid >> 6;

  __shared__ float qs[4][64];   // per-wave q row
  __shared__ float ps[4][64];   // per-wave p vector (wave-private, no barrier)

  int row = i0 + wv;
  qs[wv][lane] = in_item[((size_t)b * Ti + row) * 64 + lane];

  float Wsum = 0.f;
  #pragma unroll
  for (int j = 0; j < 64; ++j) Wsum += W_final[j];   // uniform -> s_loads
  const float c1 = L2E * Wsum;
  const float4* Wf4 = reinterpret_cast<const float4*>(W_final);

  int ilen = in_len[b], mlen = mem_len[b];
  const bool row_valid = row < ilen;

  const float4* mT4 = reinterpret_cast<const float4*>(mem_itemT);
  const int bb16 = b * 16;
  const float* memb = memory + (size_t)b * Tm * DM + (size_t)lane * 4;

  float psum = 0.f;
  float2v ax = {0.f, 0.f}, az = {0.f, 0.f};   // out[row][4*lane .. 4*lane+4)

  const float4*  qrow4 = reinterpret_cast<const float4*>(qs[wv]);
  const float2v* ps2   = reinterpret_cast<const float2v*>(ps[wv]);

  #pragma unroll 1
  for (int t = 0; t < NT; ++t) {
    int m0 = m_begin + t * MT;

    // ---- score for m = m0 + lane (coalesced global reads of mem_itemT) ----
    float4 S4 = make_float4(0.f, 0.f, 0.f, 0.f);
    #pragma unroll 4
    for (int d4 = 0; d4 < 16; ++d4) {
      float4 mv = mT4[(size_t)(bb16 + d4) * 1024 + m0 + lane];
      float4 qv = qrow4[d4];
      float4 w  = Wf4[d4];
      S4.x = fmaf(w.x, __builtin_amdgcn_rcpf(1.0f + __builtin_amdgcn_exp2f(qv.x + mv.x)), S4.x);
      S4.y = fmaf(w.y, __builtin_amdgcn_rcpf(1.0f + __builtin_amdgcn_exp2f(qv.y + mv.y)), S4.y);
      S4.z = fmaf(w.z, __builtin_amdgcn_rcpf(1.0f + __builtin_amdgcn_exp2f(qv.z + mv.z)), S4.z);
      S4.w = fmaf(w.w, __builtin_amdgcn_rcpf(1.0f + __builtin_amdgcn_exp2f(qv.w + mv.w)), S4.w);
    }
    float S = (S4.x + S4.y) + (S4.z + S4.w);
    int mi = m0 + lane;
    float p = row_valid ? ((mi < mlen) ? __builtin_amdgcn_exp2f(fmaf(-C2, S, c1)) : 0.f)
                        : 1.0f;
    ps[wv][lane] = p;      // wave-private; lgkmcnt orders vs reads below
    psum += p;

    // ---- PV: lane owns d-quad; p pairs via broadcast ds_read_b64 ----
    const float* mpb = memb + (size_t)m0 * DM;
    #pragma unroll 4
    for (int mm = 0; mm < 32; ++mm) {
      float2v pp = ps2[mm];   // uniform address -> broadcast, conflict-free
      float4 v0 = *reinterpret_cast<const float4*>(mpb + (size_t)(2 * mm) * DM);
      float4 v1 = *reinterpret_cast<const float4*>(mpb + (size_t)(2 * mm + 1) * DM);
      ax = pk_fma_bl(float2v{v0.x, v0.y}, pp, ax);
      az = pk_fma_bl(float2v{v0.z, v0.w}, pp, az);
      ax = pk_fma_bh(float2v{v1.x, v1.y}, pp, ax);
      az = pk_fma_bh(float2v{v1.z, v1.w}, pp, az);
    }
  }

  // ---- epilogue: lane-reduce psum, write own row (no cross-wave traffic) ----
  float s = psum;
  #pragma unroll
  for (int o = 32; o >= 1; o >>= 1) s += __shfl_xor(s, o);

  size_t r = (size_t)b * Ti + row;
  reinterpret_cast<float4*>(o_part)[((size_t)z * 2048 + r) * 64 + lane] =
      make_float4(ax.x, ax.y, az.x, az.y);
  if (lane == 0) psum_part[(size_t)z * 2048 + r] = s;
}

// ---------------- Combine: out = sum_z o_part / sum_z psum
__global__ __launch_bounds__(256) void combine_kernel(
    const float* __restrict__ o_part, const float* __restrict__ psum_part,
    float* __restrict__ out, int nsplit)
{
  int e = blockIdx.x * 256 + threadIdx.x;   // float4 index, 0..131071
  int r = e >> 6;
  const float4* op4 = reinterpret_cast<const float4*>(o_part);
  float4 o = make_float4(0.f, 0.f, 0.f, 0.f);
  float s = 0.f;
  for (int zi = 0; zi < nsplit; ++zi) {
    float4 t = op4[(size_t)zi * 131072 + e];
    o.x += t.x; o.y += t.y; o.z += t.z; o.w += t.w;
    s += psum_part[(size_t)zi * 2048 + r];
  }
  float inv = __builtin_amdgcn_rcpf(s);
  o.x *= inv; o.y *= inv; o.z *= inv; o.w *= inv;
  reinterpret_cast<float4*>(out)[e] = o;
}

extern "C" void kernel_launch(void* const* d_in, const int* in_sizes, int n_in,
                              void* d_out, int out_size, void* d_ws, size_t ws_size,
                              hipStream_t stream) {
  const float* inputs   = (const float*)d_in[0];  // (4,512,256)
  const float* memory   = (const float*)d_in[1];  // (4,1024,256)
  const int*   in_len   = (const int*)  d_in[2];  // (4)
  const int*   mem_len  = (const int*)  d_in[3];  // (4)
  const float* W_in     = (const float*)d_in[4];  // (64,256)
  const float* b_in     = (const float*)d_in[5];  // (64)
  const float* W_mem    = (const float*)d_in[6];  // (64,256)
  const float* W_final  = (const float*)d_in[7];  // (64)
  float* out = (float*)d_out;                     // (4,512,256)

  float* in_item   = (float*)d_ws;                  // 512 KB
  float* mem_itemT = in_item + 2048 * 64;           // 1 MB
  float* o_part    = mem_itemT + 4096 * 64;         // up to 8 MB
  // psum_part placed after max o_part extent (allocated below per nsplit)

  size_t base_f  = 131072 + 262144;                         // in_item + mem_itemT
  size_t need4 = (base_f + 4 * 524288 + 4 * 2048 + 64) * 4; // ~9.97 MB
  size_t need2 = (base_f + 2 * 524288 + 2 * 2048 + 64) * 4; // ~5.77 MB
  int nsplit, shift;
  if      (ws_size >= need4) { nsplit = 4; shift = 4; }
  else if (ws_size >= need2) { nsplit = 2; shift = 3; }
  else                       { nsplit = 1; shift = 2; }
  float* psum_part = o_part + (size_t)nsplit * 2048 * 256;

  proj_kernel<<<1536, 256, 0, stream>>>(inputs, memory, W_in, b_in, W_mem,
                                        in_item, mem_itemT);
  attn_kernel<<<dim3(512 * nsplit), 256, 0, stream>>>(
      in_item, mem_itemT, memory, in_len, mem_len, W_final,
      o_part, psum_part, 1024 / nsplit, shift);
  combine_kernel<<<512, 256, 0, stream>>>(o_part, psum_part, out, nsplit);
}